// Round 4
// baseline (30.852 us; speedup 1.0000x reference)
//
#include <hip/hip_runtime.h>

#define Wd 512
#define Hd 512
#define NIMG 48                       // 16 batch * 3 channels
#define ROWS 4                        // output rows per wave-strip
#define NSTRIPS (NIMG * (Hd / ROWS))  // 48 * 128 = 6144, one wave (=block) each
constexpr float INV_N = 1.0f / (float)((long long)NIMG * Hd * Wd);

// Scharr on a 3x10 window; pixel j (0..7) uses cols j..j+2 of rows r0,r1,r2.
__device__ __forceinline__ float scharr_pix(const float r0[10], const float r1[10],
                                            const float r2[10], int j) {
    float tl = r0[j], tm = r0[j + 1], tr = r0[j + 2];
    float ml = r1[j],                  mr = r1[j + 2];
    float bl = r2[j], bm = r2[j + 1], br = r2[j + 2];
    float gx = 3.f * (tr - tl) + 10.f * (mr - ml) + 3.f * (br - bl);
    float gy = 3.f * (bl - tl) + 10.f * (bm - tm) + 3.f * (br - tr);
    return fabsf(gx) + fabsf(gy);
}

// Load cols [c0-1 .. c0+8] of row h. Lane covers 8 cols via two float4s;
// horizontal halo via neighbor-lane shfl (wave spans the full 512-col row,
// so lane edges == image edges -> zero). h is wave-uniform -> no divergence.
__device__ __forceinline__ void load_row(const float* __restrict__ img, int h,
                                         int c0, int lane, float r[10]) {
    if ((unsigned)h < (unsigned)Hd) {
        const float* p = img + (size_t)h * Wd + c0;
        float4 b0 = *reinterpret_cast<const float4*>(p);
        float4 b1 = *reinterpret_cast<const float4*>(p + 4);
        r[1] = b0.x; r[2] = b0.y; r[3] = b0.z; r[4] = b0.w;
        r[5] = b1.x; r[6] = b1.y; r[7] = b1.z; r[8] = b1.w;
        float lv = __shfl_up(b1.w, 1, 64);    // lane-1's col c0-1
        float rv = __shfl_down(b0.x, 1, 64);  // lane+1's col c0+8
        r[0] = (lane > 0)  ? lv : 0.f;        // image left edge -> 0
        r[9] = (lane < 63) ? rv : 0.f;        // image right edge -> 0
    } else {
        #pragma unroll
        for (int k = 0; k < 10; ++k) r[k] = 0.f;
    }
}

__global__ void __launch_bounds__(64)
scharr_loss_kernel(const float* __restrict__ x, const float* __restrict__ gt,
                   float* __restrict__ partials) {
    int lane  = threadIdx.x;
    int strip = blockIdx.x;               // 0 .. NSTRIPS-1
    int img   = strip >> 7;               // 128 strips per image
    int h0    = (strip & 127) * ROWS;
    int c0    = lane * 8;

    const float* __restrict__ xb = x  + (size_t)img * Hd * Wd;
    const float* __restrict__ gb = gt + (size_t)img * Hd * Wd;

    // Rolling 3-row windows, fully unrolled -> all indices compile-time.
    float rx[3][10], rg[3][10];
    load_row(xb, h0 - 1, c0, lane, rx[0]);
    load_row(xb, h0,     c0, lane, rx[1]);
    load_row(gb, h0 - 1, c0, lane, rg[0]);
    load_row(gb, h0,     c0, lane, rg[1]);

    float sum = 0.f;
    #pragma unroll
    for (int i = 0; i < ROWS; ++i) {
        const int c0i = i % 3, c1i = (i + 1) % 3, c2i = (i + 2) % 3;
        load_row(xb, h0 + i + 1, c0, lane, rx[c2i]);
        load_row(gb, h0 + i + 1, c0, lane, rg[c2i]);
        #pragma unroll
        for (int j = 0; j < 8; ++j) {
            float a = scharr_pix(rx[c0i], rx[c1i], rx[c2i], j);
            float b = scharr_pix(rg[c0i], rg[c1i], rg[c2i], j);
            sum += fabsf(a - b);
        }
    }

    // wave(64) reduce; one plain store per wave. No LDS, no syncthreads.
    #pragma unroll
    for (int off = 32; off > 0; off >>= 1)
        sum += __shfl_down(sum, off, 64);
    if (lane == 0)
        partials[blockIdx.x] = sum;
}

__global__ void __launch_bounds__(256)
reduce_partials_kernel(const float* __restrict__ partials, float* __restrict__ out) {
    float s = 0.f;
    #pragma unroll
    for (int k = 0; k < NSTRIPS / 256; ++k)      // 24 iterations
        s += partials[k * 256 + threadIdx.x];
    #pragma unroll
    for (int off = 32; off > 0; off >>= 1)
        s += __shfl_down(s, off, 64);
    __shared__ float ws[4];
    int lane = threadIdx.x & 63;
    int wid  = threadIdx.x >> 6;
    if (lane == 0) ws[wid] = s;
    __syncthreads();
    if (threadIdx.x == 0)
        out[0] = (ws[0] + ws[1] + ws[2] + ws[3]) * INV_N;
}

extern "C" void kernel_launch(void* const* d_in, const int* in_sizes, int n_in,
                              void* d_out, int out_size, void* d_ws, size_t ws_size,
                              hipStream_t stream) {
    const float* x  = (const float*)d_in[0];
    const float* gt = (const float*)d_in[1];
    float* out      = (float*)d_out;
    float* partials = (float*)d_ws;       // NSTRIPS floats = 24.6 KB

    scharr_loss_kernel<<<NSTRIPS, 64, 0, stream>>>(x, gt, partials);
    reduce_partials_kernel<<<1, 256, 0, stream>>>(partials, out);
}

// Round 5
// 24.977 us; speedup vs baseline: 1.2352x; 1.2352x over previous
//
#include <hip/hip_runtime.h>

#define Wd 512
#define Hd 512
#define NIMG 48                      // 16 batch * 3 channels
#define RB 16                        // output rows per block
#define LR (RB + 2)                  // staged rows incl. vertical halo
#define NBLK (NIMG * (Hd / RB))      // 48*32 = 1536 blocks
constexpr float INV_N = 1.0f / (float)((long long)NIMG * Hd * Wd);

// async global->LDS, 16 B per lane: lane l writes lds_base + l*16.
__device__ __forceinline__ void gload_lds16(const float* g, float* l) {
    __builtin_amdgcn_global_load_lds(
        (const __attribute__((address_space(1))) void*)g,
        (__attribute__((address_space(3))) void*)l, 16, 0, 0);
}

// Scharr on a 3x10 window; pixel j (0..7) uses cols j..j+2 of rows r0,r1,r2.
__device__ __forceinline__ float scharr_pix(const float r0[10], const float r1[10],
                                            const float r2[10], int j) {
    float tl = r0[j], tm = r0[j + 1], tr = r0[j + 2];
    float ml = r1[j],                  mr = r1[j + 2];
    float bl = r2[j], bm = r2[j + 1], br = r2[j + 2];
    float gx = 3.f * (tr - tl) + 10.f * (mr - ml) + 3.f * (br - bl);
    float gy = 3.f * (bl - tl) + 10.f * (bm - tm) + 3.f * (br - tr);
    return fabsf(gx) + fabsf(gy);
}

// Read cols [c0-1 .. c0+8] of one staged LDS row; halo via neighbor-lane shfl
// (wave spans the full 512-col row, lane edges == image edges -> zero).
__device__ __forceinline__ void lds_row(const float* __restrict__ row, int lane,
                                        float r[10]) {
    float4 b0 = *reinterpret_cast<const float4*>(row + lane * 8);
    float4 b1 = *reinterpret_cast<const float4*>(row + lane * 8 + 4);
    r[1] = b0.x; r[2] = b0.y; r[3] = b0.z; r[4] = b0.w;
    r[5] = b1.x; r[6] = b1.y; r[7] = b1.z; r[8] = b1.w;
    float lv = __shfl_up(b1.w, 1, 64);     // lane-1's col c0-1
    float rv = __shfl_down(b0.x, 1, 64);   // lane+1's col c0+8
    r[0] = (lane > 0)  ? lv : 0.f;
    r[9] = (lane < 63) ? rv : 0.f;
}

__global__ void __launch_bounds__(256)
scharr_loss_kernel(const float* __restrict__ x, const float* __restrict__ gt,
                   float* __restrict__ partials) {
    __shared__ float lb[2][LR][Wd];      // 72 KB: both images' 18-row tile
    __shared__ float ws[4];

    int wid  = threadIdx.x >> 6;
    int lane = threadIdx.x & 63;

    // Bijective XCD swizzle (NBLK % 8 == 0): each XCD gets contiguous tiles,
    // so block-boundary halo rows are same-XCD L2 hits.
    int b   = blockIdx.x;
    int swz = (b & 7) * (NBLK / 8) + (b >> 3);
    int img = swz >> 5;                  // 32 tiles per image
    int h0  = (swz & 31) * RB;

    const float* __restrict__ xb = x  + (size_t)img * Hd * Wd;
    const float* __restrict__ gb = gt + (size_t)img * Hd * Wd;

    // --- stage: wave w loads img (w>>1), half-row (w&1), for all LR rows ---
    int is   = wid >> 1;                 // which image
    int half = wid & 1;                  // which 256-float half of the row
    const float* __restrict__ sb = is ? gb : xb;
    #pragma unroll
    for (int t = 0; t < LR; ++t) {
        int gh = h0 - 1 + t;
        float* dst = &lb[is][t][half * 256];
        if ((unsigned)gh < (unsigned)Hd) {
            gload_lds16(sb + (size_t)gh * Wd + half * 256 + lane * 4, dst);
        } else {
            *reinterpret_cast<float4*>(dst + lane * 4) =
                make_float4(0.f, 0.f, 0.f, 0.f);
        }
    }
    __syncthreads();                     // vmcnt(0) drain, once per block

    // --- compute: wave w owns 4 consecutive output rows, rolling window ---
    int r0 = wid * 4;                    // local output row base (0,4,8,12)
    float rx[3][10], rg[3][10];
    lds_row(&lb[0][r0][0],     lane, rx[0]);
    lds_row(&lb[0][r0 + 1][0], lane, rx[1]);
    lds_row(&lb[1][r0][0],     lane, rg[0]);
    lds_row(&lb[1][r0 + 1][0], lane, rg[1]);

    float sum = 0.f;
    #pragma unroll
    for (int i = 0; i < 4; ++i) {
        const int c0 = i % 3, c1 = (i + 1) % 3, c2 = (i + 2) % 3;
        lds_row(&lb[0][r0 + i + 2][0], lane, rx[c2]);
        lds_row(&lb[1][r0 + i + 2][0], lane, rg[c2]);
        #pragma unroll
        for (int j = 0; j < 8; ++j) {
            float a = scharr_pix(rx[c0], rx[c1], rx[c2], j);
            float g = scharr_pix(rg[c0], rg[c1], rg[c2], j);
            sum += fabsf(a - g);
        }
    }

    // wave reduce -> cross-wave LDS -> one plain store per block
    #pragma unroll
    for (int off = 32; off > 0; off >>= 1)
        sum += __shfl_down(sum, off, 64);
    if (lane == 0) ws[wid] = sum;
    __syncthreads();
    if (threadIdx.x == 0)
        partials[blockIdx.x] = ws[0] + ws[1] + ws[2] + ws[3];
}

__global__ void __launch_bounds__(256)
reduce_partials_kernel(const float* __restrict__ partials, float* __restrict__ out) {
    float s = 0.f;
    #pragma unroll
    for (int k = 0; k < NBLK / 256; ++k)          // 6 iterations
        s += partials[k * 256 + threadIdx.x];
    #pragma unroll
    for (int off = 32; off > 0; off >>= 1)
        s += __shfl_down(s, off, 64);
    __shared__ float ws[4];
    int lane = threadIdx.x & 63;
    int wid  = threadIdx.x >> 6;
    if (lane == 0) ws[wid] = s;
    __syncthreads();
    if (threadIdx.x == 0)
        out[0] = (ws[0] + ws[1] + ws[2] + ws[3]) * INV_N;
}

extern "C" void kernel_launch(void* const* d_in, const int* in_sizes, int n_in,
                              void* d_out, int out_size, void* d_ws, size_t ws_size,
                              hipStream_t stream) {
    const float* x  = (const float*)d_in[0];
    const float* gt = (const float*)d_in[1];
    float* out      = (float*)d_out;
    float* partials = (float*)d_ws;      // NBLK floats = 6 KB

    scharr_loss_kernel<<<NBLK, 256, 0, stream>>>(x, gt, partials);
    reduce_partials_kernel<<<1, 256, 0, stream>>>(partials, out);
}